// Round 3
// baseline (3718.421 us; speedup 1.0000x reference)
//
#include <hip/hip_runtime.h>
#include <hip/hip_bf16.h>

// EquivariantBlock (EGNN layer) — Round 3: fp32 in / fp32 out.
// Evidence: R1 all-bf16 reads -> NaN (fp32 data read as bf16 hits exp=0xFF);
// R2 runtime probe ran the fp32 branch -> finite. Inputs fp32. R2's absmax
// 5.125 == max|ref| 4.85 + silu-min 0.278: bf16-written output read as fp32
// by the harness (pairing error), upper half zero. So output is fp32 too.
// Pipeline: zero -> node_lin -> edge1(att+msg, atomicAdd agg) -> node2(MLP+LN+silu)
//           -> edge2(coord MLP, atomicAdd aggx) -> coord epilogue.

#define D 128
#define DP (D + 4)   // +4 float pad: breaks bank conflicts in per-edge reductions
#define TE 16        // edges per block in edge kernels

__device__ __forceinline__ float siluf(float x) { return x / (1.0f + __expf(-x)); }
__device__ __forceinline__ float sigmf(float x) { return 1.0f / (1.0f + __expf(-x)); }

// ---------------- zero scratch ----------------
__global__ void k_zero(float* __restrict__ p, long n) {
    long i = (long)blockIdx.x * blockDim.x + threadIdx.x;
    long stride = (long)gridDim.x * blockDim.x;
    for (; i < n; i += stride) p[i] = 0.0f;
}

// ---------------- hh = h @ W_lin + b_lin ----------------
__global__ __launch_bounds__(128) void k_node_lin(
    const float* __restrict__ h, const float* __restrict__ W,
    const float* __restrict__ b, float* __restrict__ hh) {
    const int i = blockIdx.x, j = threadIdx.x;
    __shared__ alignas(16) float hs[D];
    hs[j] = h[i * D + j];
    __syncthreads();
    float acc = b[j];
#pragma unroll 4
    for (int k = 0; k < D; k += 4) {
        const float4 v = *(const float4*)&hs[k];
        acc += v.x * W[(k + 0) * D + j];
        acc += v.y * W[(k + 1) * D + j];
        acc += v.z * W[(k + 2) * D + j];
        acc += v.w * W[(k + 3) * D + j];
    }
    hh[i * D + j] = acc;
}

// ---------------- edge phase 1: attention + message -> agg ----------------
__global__ __launch_bounds__(256) void k_edge1(
    const int* __restrict__ eidx, const float* __restrict__ x,
    const float* __restrict__ eattr, const float* __restrict__ emask,
    const float* __restrict__ hh,
    const float* __restrict__ Wa1, const float* __restrict__ ba1,
    const float* __restrict__ Wa2, const float* __restrict__ ba2,
    const float* __restrict__ We1, const float* __restrict__ be1,
    const float* __restrict__ We2, const float* __restrict__ be2,
    float* __restrict__ agg, float2* __restrict__ e3buf, int E) {
    __shared__ alignas(16) float hr_s[TE][DP];
    __shared__ alignas(16) float hc_s[TE][DP];
    __shared__ alignas(16) float d_s[TE][DP];
    __shared__ alignas(16) float m_s[TE][DP];
    __shared__ float part_s[TE][17];
    __shared__ float dist_s[TE], attr_s[TE], geo_s[TE], att_s[TE], em_s[TE];
    __shared__ int row_s[TE], col_s[TE];
    __shared__ float wa2_s[D];

    const int t = threadIdx.x;
    const int j = t & (D - 1);
    const int eb = (t >> 7) * 8;   // threads 0..127 -> edges 0..7; 128..255 -> 8..15
    const int base = blockIdx.x * TE;

    if (t < TE) {
        const int e = base + t;
        int r = 0, c = 0;
        float dist = 0.f, at = 0.f, em = 0.f;
        if (e < E) {
            r = eidx[e];
            c = eidx[E + e];
            const float dx = x[r * 3 + 0] - x[c * 3 + 0];
            const float dy = x[r * 3 + 1] - x[c * 3 + 1];
            const float dz = x[r * 3 + 2] - x[c * 3 + 2];
            dist = sqrtf(dx * dx + dy * dy + dz * dz + 1e-8f);
            at = eattr[e];
            em = emask[e];
        }
        row_s[t] = r; col_s[t] = c;
        dist_s[t] = dist; attr_s[t] = at; em_s[t] = em;
    }
    if (t < D) wa2_s[t] = Wa2[t];
    __syncthreads();

#pragma unroll
    for (int e = 0; e < 8; e++) {
        const int ee = eb + e;
        const float a = hh[row_s[ee] * D + j];
        const float b = hh[col_s[ee] * D + j];
        hr_s[ee][j] = a;
        hc_s[ee][j] = b;
        d_s[ee][j] = b - a;   // hc - hr (matches msg_in)
    }
    __syncthreads();

    // geo = ||hr-hc||: 16 partials per edge, then 16-lane finish
    {
        const int el = t >> 4, k0 = (t & 15) * 8;
        float s = 0.f;
#pragma unroll
        for (int k = 0; k < 8; k++) { const float v = d_s[el][k0 + k]; s += v * v; }
        part_s[el][t & 15] = s;
    }
    __syncthreads();
    if (t < TE) {
        float s = 0.f;
#pragma unroll
        for (int k = 0; k < 16; k++) s += part_s[t][k];
        const float g = sqrtf(s + 1e-8f);
        geo_s[t] = g;
        const int e = base + t;
        if (e < E) e3buf[e] = make_float2(dist_s[t], g);
    }
    __syncthreads();

    float acc[8];
    // GEMM1: a1 = silu([hr, hc, e3] @ Wa1 + ba1)   (Wa1: (259,128) row-major)
    {
        const float bj = ba1[j];
#pragma unroll
        for (int e = 0; e < 8; e++) acc[e] = bj;
        for (int k = 0; k < D; k += 4) {
            const float w0 = Wa1[(k + 0) * D + j];
            const float w1 = Wa1[(k + 1) * D + j];
            const float w2 = Wa1[(k + 2) * D + j];
            const float w3 = Wa1[(k + 3) * D + j];
#pragma unroll
            for (int e = 0; e < 8; e++) {
                const float4 v = *(const float4*)&hr_s[eb + e][k];
                acc[e] += v.x * w0 + v.y * w1 + v.z * w2 + v.w * w3;
            }
        }
        for (int k = 0; k < D; k += 4) {
            const float w0 = Wa1[(D + k + 0) * D + j];
            const float w1 = Wa1[(D + k + 1) * D + j];
            const float w2 = Wa1[(D + k + 2) * D + j];
            const float w3 = Wa1[(D + k + 3) * D + j];
#pragma unroll
            for (int e = 0; e < 8; e++) {
                const float4 v = *(const float4*)&hc_s[eb + e][k];
                acc[e] += v.x * w0 + v.y * w1 + v.z * w2 + v.w * w3;
            }
        }
        const float wd = Wa1[256 * D + j];
        const float wa = Wa1[257 * D + j];
        const float wg = Wa1[258 * D + j];
#pragma unroll
        for (int e = 0; e < 8; e++) {
            const int ee = eb + e;
            acc[e] += dist_s[ee] * wd + attr_s[ee] * wa + geo_s[ee] * wg;
            m_s[ee][j] = siluf(acc[e]);   // a1 -> m_s
        }
    }
    __syncthreads();

    // att = sigmoid(a1 @ Wa2 + ba2) * edge_mask
    if (t < TE) {
        float s = ba2[0];
        for (int k = 0; k < D; k++) s += m_s[t][k] * wa2_s[k];
        att_s[t] = sigmf(s) * em_s[t];
    }
    __syncthreads();

    // GEMM2: m1 = silu([hc-hr, e3] @ We1 + be1)   (We1: (131,128))
    {
        const float bj = be1[j];
#pragma unroll
        for (int e = 0; e < 8; e++) acc[e] = bj;
        for (int k = 0; k < D; k += 4) {
            const float w0 = We1[(k + 0) * D + j];
            const float w1 = We1[(k + 1) * D + j];
            const float w2 = We1[(k + 2) * D + j];
            const float w3 = We1[(k + 3) * D + j];
#pragma unroll
            for (int e = 0; e < 8; e++) {
                const float4 v = *(const float4*)&d_s[eb + e][k];
                acc[e] += v.x * w0 + v.y * w1 + v.z * w2 + v.w * w3;
            }
        }
        const float wd = We1[128 * D + j];
        const float wa = We1[129 * D + j];
        const float wg = We1[130 * D + j];
#pragma unroll
        for (int e = 0; e < 8; e++) {
            const int ee = eb + e;
            acc[e] += dist_s[ee] * wd + attr_s[ee] * wa + geo_s[ee] * wg;
        }
        __syncthreads();   // att readers of m_s are done; safe to overwrite
#pragma unroll
        for (int e = 0; e < 8; e++) m_s[eb + e][j] = siluf(acc[e]);
    }
    __syncthreads();

    // GEMM3: msg = (m1 @ We2 + be2) * att ; atomicAdd into agg[row]
    {
        const float bj = be2[j];
#pragma unroll
        for (int e = 0; e < 8; e++) acc[e] = bj;
        for (int k = 0; k < D; k += 4) {
            const float w0 = We2[(k + 0) * D + j];
            const float w1 = We2[(k + 1) * D + j];
            const float w2 = We2[(k + 2) * D + j];
            const float w3 = We2[(k + 3) * D + j];
#pragma unroll
            for (int e = 0; e < 8; e++) {
                const float4 v = *(const float4*)&m_s[eb + e][k];
                acc[e] += v.x * w0 + v.y * w1 + v.z * w2 + v.w * w3;
            }
        }
#pragma unroll
        for (int e = 0; e < 8; e++) {
            const int ee = eb + e;
            if (base + ee < E) {
                atomicAdd(&agg[row_s[ee] * D + j], acc[e] * att_s[ee]);
            }
        }
    }
}

// ---------------- node MLP + residual + LayerNorm + silu ----------------
__global__ __launch_bounds__(128) void k_node2(
    const float* __restrict__ agg, float* __restrict__ hh,
    const float* __restrict__ Wn1, const float* __restrict__ bn1,
    const float* __restrict__ Wn2, const float* __restrict__ bn2,
    const float* __restrict__ ln_g, const float* __restrict__ ln_b,
    float* __restrict__ out_h) {
    const int i = blockIdx.x, j = threadIdx.x;
    __shared__ alignas(16) float ag[D];
    __shared__ alignas(16) float t1[D];
    __shared__ float red[D];
    ag[j] = agg[i * D + j];
    const float hv = hh[i * D + j];
    __syncthreads();

    float acc = bn1[j];
#pragma unroll 4
    for (int k = 0; k < D; k += 4) {
        const float4 v = *(const float4*)&ag[k];
        acc += v.x * Wn1[(k + 0) * D + j];
        acc += v.y * Wn1[(k + 1) * D + j];
        acc += v.z * Wn1[(k + 2) * D + j];
        acc += v.w * Wn1[(k + 3) * D + j];
    }
    t1[j] = siluf(acc);
    __syncthreads();

    acc = bn2[j];
#pragma unroll 4
    for (int k = 0; k < D; k += 4) {
        const float4 v = *(const float4*)&t1[k];
        acc += v.x * Wn2[(k + 0) * D + j];
        acc += v.y * Wn2[(k + 1) * D + j];
        acc += v.z * Wn2[(k + 2) * D + j];
        acc += v.w * Wn2[(k + 3) * D + j];
    }
    const float v = hv + acc;

    red[j] = v;
    __syncthreads();
    for (int s = 64; s > 0; s >>= 1) {
        if (j < s) red[j] += red[j + s];
        __syncthreads();
    }
    const float mu = red[0] * (1.0f / D);
    __syncthreads();
    const float dv = v - mu;
    red[j] = dv * dv;
    __syncthreads();
    for (int s = 64; s > 0; s >>= 1) {
        if (j < s) red[j] += red[j + s];
        __syncthreads();
    }
    const float var = red[0] * (1.0f / D);

    const float hn = dv * rsqrtf(var + 1e-5f) * ln_g[j] + ln_b[j];
    const float o = siluf(hn);
    out_h[i * D + j] = o;
    hh[i * D + j] = o;   // in-place: block i owns row i; read happened before syncs
}

// ---------------- edge phase 2: coord MLP -> aggx ----------------
__global__ __launch_bounds__(256) void k_edge2(
    const int* __restrict__ eidx, const float* __restrict__ x,
    const float* __restrict__ eattr, const float* __restrict__ emask,
    const float* __restrict__ hh, const float2* __restrict__ e3buf,
    const float* __restrict__ Wc1, const float* __restrict__ bc1,
    const float* __restrict__ Wc2, const float* __restrict__ bc2,
    const float* __restrict__ Wc3, float* __restrict__ aggx, int E) {
    __shared__ alignas(16) float hr_s[TE][DP];
    __shared__ alignas(16) float hc_s[TE][DP];
    __shared__ alignas(16) float c1_s[TE][DP];
    __shared__ float dist_s[TE], attr_s[TE], geo_s[TE], em_s[TE];
    __shared__ float cdx_s[TE], cdy_s[TE], cdz_s[TE];
    __shared__ int row_s[TE], col_s[TE];
    __shared__ float wc3_s[D];

    const int t = threadIdx.x;
    const int j = t & (D - 1);
    const int eb = (t >> 7) * 8;
    const int base = blockIdx.x * TE;

    if (t < TE) {
        const int e = base + t;
        int r = 0, c = 0;
        float dist = 1.f, geo = 0.f, at = 0.f, em = 0.f, cdx = 0.f, cdy = 0.f, cdz = 0.f;
        if (e < E) {
            r = eidx[e];
            c = eidx[E + e];
            const float2 dg = e3buf[e];
            dist = dg.x; geo = dg.y;
            at = eattr[e];
            em = emask[e];
            const float inv = 1.0f / (dist + 1.0f);   // NORM_CONST = 1
            cdx = (x[r * 3 + 0] - x[c * 3 + 0]) * inv;
            cdy = (x[r * 3 + 1] - x[c * 3 + 1]) * inv;
            cdz = (x[r * 3 + 2] - x[c * 3 + 2]) * inv;
        }
        row_s[t] = r; col_s[t] = c;
        dist_s[t] = dist; geo_s[t] = geo; attr_s[t] = at; em_s[t] = em;
        cdx_s[t] = cdx; cdy_s[t] = cdy; cdz_s[t] = cdz;
    }
    if (t < D) wc3_s[t] = Wc3[t];
    __syncthreads();

#pragma unroll
    for (int e = 0; e < 8; e++) {
        const int ee = eb + e;
        hr_s[ee][j] = hh[row_s[ee] * D + j];
        hc_s[ee][j] = hh[col_s[ee] * D + j];
    }
    __syncthreads();

    float acc[8];
    // GEMM1: c1 = silu([hr, hc, e3] @ Wc1 + bc1)   (Wc1: (259,128))
    {
        const float bj = bc1[j];
#pragma unroll
        for (int e = 0; e < 8; e++) acc[e] = bj;
        for (int k = 0; k < D; k += 4) {
            const float w0 = Wc1[(k + 0) * D + j];
            const float w1 = Wc1[(k + 1) * D + j];
            const float w2 = Wc1[(k + 2) * D + j];
            const float w3 = Wc1[(k + 3) * D + j];
#pragma unroll
            for (int e = 0; e < 8; e++) {
                const float4 v = *(const float4*)&hr_s[eb + e][k];
                acc[e] += v.x * w0 + v.y * w1 + v.z * w2 + v.w * w3;
            }
        }
        for (int k = 0; k < D; k += 4) {
            const float w0 = Wc1[(D + k + 0) * D + j];
            const float w1 = Wc1[(D + k + 1) * D + j];
            const float w2 = Wc1[(D + k + 2) * D + j];
            const float w3 = Wc1[(D + k + 3) * D + j];
#pragma unroll
            for (int e = 0; e < 8; e++) {
                const float4 v = *(const float4*)&hc_s[eb + e][k];
                acc[e] += v.x * w0 + v.y * w1 + v.z * w2 + v.w * w3;
            }
        }
        const float wd = Wc1[256 * D + j];
        const float wa = Wc1[257 * D + j];
        const float wg = Wc1[258 * D + j];
#pragma unroll
        for (int e = 0; e < 8; e++) {
            const int ee = eb + e;
            acc[e] += dist_s[ee] * wd + attr_s[ee] * wa + geo_s[ee] * wg;
            c1_s[ee][j] = siluf(acc[e]);
        }
    }
    __syncthreads();

    // GEMM2: c2 = silu(c1 @ Wc2 + bc2) -> overwrite hr_s
    {
        const float bj = bc2[j];
#pragma unroll
        for (int e = 0; e < 8; e++) acc[e] = bj;
        for (int k = 0; k < D; k += 4) {
            const float w0 = Wc2[(k + 0) * D + j];
            const float w1 = Wc2[(k + 1) * D + j];
            const float w2 = Wc2[(k + 2) * D + j];
            const float w3 = Wc2[(k + 3) * D + j];
#pragma unroll
            for (int e = 0; e < 8; e++) {
                const float4 v = *(const float4*)&c1_s[eb + e][k];
                acc[e] += v.x * w0 + v.y * w1 + v.z * w2 + v.w * w3;
            }
        }
#pragma unroll
        for (int e = 0; e < 8; e++) hr_s[eb + e][j] = siluf(acc[e]);
    }
    __syncthreads();

    // m = c2 @ Wc3 (bias-free); trans = coord_diff * m * edge_mask
    if (t < TE) {
        float m = 0.f;
        for (int k = 0; k < D; k++) m += hr_s[t][k] * wc3_s[k];
        const int e = base + t;
        if (e < E) {
            const float tr = m * em_s[t];
            const int r4 = row_s[t] * 4;
            atomicAdd(&aggx[r4 + 0], cdx_s[t] * tr);
            atomicAdd(&aggx[r4 + 1], cdy_s[t] * tr);
            atomicAdd(&aggx[r4 + 2], cdz_s[t] * tr);
        }
    }
}

// ---------------- coord epilogue ----------------
__global__ void k_coord(const float* __restrict__ x, const float* __restrict__ nmask,
                        const float* __restrict__ aggx, float* __restrict__ out_x, int N) {
    const int idx = blockIdx.x * blockDim.x + threadIdx.x;
    if (idx >= N * 3) return;
    const int i = idx / 3, d = idx - i * 3;
    out_x[idx] = (x[idx] + aggx[i * 4 + d] * (1.0f / 100.0f)) * nmask[i];
}

extern "C" void kernel_launch(void* const* d_in, const int* in_sizes, int n_in,
                              void* d_out, int out_size, void* d_ws, size_t ws_size,
                              hipStream_t stream) {
    const float* h     = (const float*)d_in[0];
    const float* x     = (const float*)d_in[1];
    const int*   eidx  = (const int*)d_in[2];
    const float* nmask = (const float*)d_in[3];
    const float* emask = (const float*)d_in[4];
    const float* eattr = (const float*)d_in[5];
    const float* W_lin = (const float*)d_in[6];
    const float* b_lin = (const float*)d_in[7];
    const float* We1   = (const float*)d_in[8];
    const float* be1   = (const float*)d_in[9];
    const float* We2   = (const float*)d_in[10];
    const float* be2   = (const float*)d_in[11];
    const float* Wn1   = (const float*)d_in[12];
    const float* bn1   = (const float*)d_in[13];
    const float* Wn2   = (const float*)d_in[14];
    const float* bn2   = (const float*)d_in[15];
    const float* Wa1   = (const float*)d_in[16];
    const float* ba1   = (const float*)d_in[17];
    const float* Wa2   = (const float*)d_in[18];
    const float* ba2   = (const float*)d_in[19];
    const float* ln_g  = (const float*)d_in[20];
    const float* ln_b  = (const float*)d_in[21];
    const float* Wc1   = (const float*)d_in[22];
    const float* bc1   = (const float*)d_in[23];
    const float* Wc2   = (const float*)d_in[24];
    const float* bc2   = (const float*)d_in[25];
    const float* Wc3   = (const float*)d_in[26];

    const int N = in_sizes[0] / D;
    const int E = in_sizes[2] / 2;

    // ws layout (fp32): hh[N*D] | agg[N*D] | aggx[N*4] | e3buf[E*2]  (~26 MB)
    float*  hh    = (float*)d_ws;
    float*  agg   = hh + (size_t)N * D;
    float*  aggx  = agg + (size_t)N * D;
    float2* e3buf = (float2*)(aggx + (size_t)N * 4);

    float* out_h = (float*)d_out;
    float* out_x = out_h + (size_t)N * D;

    const int EB = (E + TE - 1) / TE;

    k_zero<<<2048, 256, 0, stream>>>(agg, (long)N * D + (long)N * 4);
    k_node_lin<<<N, 128, 0, stream>>>(h, W_lin, b_lin, hh);
    k_edge1<<<EB, 256, 0, stream>>>(eidx, x, eattr, emask, hh,
                                    Wa1, ba1, Wa2, ba2, We1, be1, We2, be2,
                                    agg, e3buf, E);
    k_node2<<<N, 128, 0, stream>>>(agg, hh, Wn1, bn1, Wn2, bn2, ln_g, ln_b, out_h);
    k_edge2<<<EB, 256, 0, stream>>>(eidx, x, eattr, emask, hh, e3buf,
                                    Wc1, bc1, Wc2, bc2, Wc3, aggx, E);
    k_coord<<<(N * 3 + 255) / 256, 256, 0, stream>>>(x, nmask, aggx, out_x, N);
}

// Round 4
// 697.943 us; speedup vs baseline: 5.3277x; 5.3277x over previous
//
#include <hip/hip_runtime.h>
#include <hip/hip_bf16.h>

// EquivariantBlock — Round 4: MFMA (bf16) edge kernels.
// R3 counters: k_edge1 96% VALUBusy, MfmaUtil 0, HBM 3% -> compute-bound on fp32 VALU.
// Edge GEMMs (85+63 GFLOP) moved to v_mfma_f32_16x16x32_bf16:
//  - block = 64 edges x 128 cols, 4 waves in 2x2 M/N partition (wave: 32 edges x 64 cols)
//  - A-frags from LDS (gathered bf16 hh rows, +16B pad), B-frags from pre-packed
//    global bf16 weights in fragment order (1 dwordx4/lane, L1/L2 resident)
//  - [hr|hc]@W folded to hr@(Wr+Wc) + d@Wc (d = hc-hr) so LDS holds hr,d only
//  - e3 (3 cols) + biases as fp32 VALU tail from original weights
//  - att/m row-dots from accumulators via shuffle + cross-wave LDS partials
// Layouts (guide-verified): A[m=lane&15][k=quad*8+j]; C/D row=quad*4+reg, col=lane&15.

#define D 128
#define TEB 64          // edges per block
#define RS 136          // LDS row stride (bf16 units): 128 + 8 pad -> 2-way conflicts max

typedef unsigned short ushort;
typedef __attribute__((ext_vector_type(8))) short short8;
typedef __attribute__((ext_vector_type(4))) float f32x4;

__device__ __forceinline__ float siluf(float x) { return x / (1.0f + __expf(-x)); }
__device__ __forceinline__ float sigmf(float x) { return 1.0f / (1.0f + __expf(-x)); }
__device__ __forceinline__ ushort f2bs(float f) {
    __hip_bfloat16 b = __float2bfloat16(f);
    ushort u; __builtin_memcpy(&u, &b, 2); return u;
}
#define MFMA16(a, b, c) __builtin_amdgcn_mfma_f32_16x16x32_bf16((a), (b), (c), 0, 0, 0)

// ---------------- zero scratch ----------------
__global__ void k_zero(float* __restrict__ p, long n) {
    long i = (long)blockIdx.x * blockDim.x + threadIdx.x;
    long stride = (long)gridDim.x * blockDim.x;
    for (; i < n; i += stride) p[i] = 0.0f;
}

// ---------------- pack weights into B-fragment order (bf16) ----------------
// dst[((ks*8+nt)*64+lane)*8+j] = W[k= ks*32+(lane>>4)*8+j][n= nt*16+(lane&15)]
// addMode: rows k<128 get W[k]+W[k+128]  (the [hr|hc] -> [hr|d] weight fold)
__global__ void k_pack(const float* __restrict__ src, ushort* __restrict__ dst,
                       int KS, int addMode) {
    const int idx = blockIdx.x * 256 + threadIdx.x;
    if (idx >= KS * 4096) return;
    const int j = idx & 7, lane = (idx >> 3) & 63, nt = (idx >> 9) & 7, ks = idx >> 12;
    const int k = ks * 32 + (lane >> 4) * 8 + j;
    const int n = nt * 16 + (lane & 15);
    float v = src[k * D + n];
    if (addMode && k < 128) v += src[(k + 128) * D + n];
    dst[idx] = f2bs(v);
}

// ---------------- hh = h @ W_lin + b_lin  (fp32 + bf16 copies) ----------------
__global__ __launch_bounds__(128) void k_node_lin(
    const float* __restrict__ h, const float* __restrict__ W,
    const float* __restrict__ b, float* __restrict__ hh,
    ushort* __restrict__ hh1b) {
    const int i = blockIdx.x, j = threadIdx.x;
    __shared__ alignas(16) float hs[D];
    hs[j] = h[i * D + j];
    __syncthreads();
    float acc = b[j];
#pragma unroll 4
    for (int k = 0; k < D; k += 4) {
        const float4 v = *(const float4*)&hs[k];
        acc += v.x * W[(k + 0) * D + j];
        acc += v.y * W[(k + 1) * D + j];
        acc += v.z * W[(k + 2) * D + j];
        acc += v.w * W[(k + 3) * D + j];
    }
    hh[i * D + j] = acc;
    hh1b[i * D + j] = f2bs(acc);
}

// ---------------- edge phase 1: att + msg -> agg (MFMA) ----------------
__global__ __launch_bounds__(256) void k_edge1(
    const int* __restrict__ eidx, const float* __restrict__ x,
    const float* __restrict__ eattr, const float* __restrict__ emask,
    const ushort* __restrict__ hh1b,
    const ushort* __restrict__ pWa1, const ushort* __restrict__ pWe1,
    const ushort* __restrict__ pWe2,
    const float* __restrict__ Wa1f, const float* __restrict__ ba1f,
    const float* __restrict__ Wa2f, const float* __restrict__ ba2f,
    const float* __restrict__ We1f, const float* __restrict__ be1f,
    const float* __restrict__ be2f,
    float* __restrict__ agg, float2* __restrict__ e3buf, int E) {
    __shared__ ushort hr_s[TEB][RS];   // hr for GEMM1; m1 overlay for GEMM3
    __shared__ ushort d_s[TEB][RS];    // hc - hr
    __shared__ float dist_s[TEB], attr_s[TEB], geo_s[TEB], att_s[TEB], em_s[TEB];
    __shared__ int row_s[TEB], col_s[TEB];
    __shared__ float attp_s[2][TEB];

    const int t = threadIdx.x;
    const int lane = t & 63, wave = t >> 6;
    const int quad = lane >> 4, l16 = lane & 15;
    const int mh = wave >> 1, nh = wave & 1;   // 2x2 wave partition
    const int base = blockIdx.x * TEB;

    // setup: per-edge scalars
    if (t < TEB) {
        const int e = base + t;
        int r = 0, c = 0; float dist = 0.f, at = 0.f, em = 0.f;
        if (e < E) {
            r = eidx[e]; c = eidx[E + e];
            const float dx = x[r * 3 + 0] - x[c * 3 + 0];
            const float dy = x[r * 3 + 1] - x[c * 3 + 1];
            const float dz = x[r * 3 + 2] - x[c * 3 + 2];
            dist = sqrtf(dx * dx + dy * dy + dz * dz + 1e-8f);
            at = eattr[e]; em = emask[e];
        }
        row_s[t] = r; col_s[t] = c;
        dist_s[t] = dist; attr_s[t] = at; em_s[t] = em;
    }
    // per-wave fp32 tail constants (cols nh*64 + nt*16 + l16)
    float t1d[4], t1a[4], t1g[4], b1[4], wa2[4], t2d[4], t2a[4], t2g[4], b2[4], b3[4];
#pragma unroll
    for (int nt = 0; nt < 4; ++nt) {
        const int col = nh * 64 + nt * 16 + l16;
        t1d[nt] = Wa1f[256 * D + col]; t1a[nt] = Wa1f[257 * D + col]; t1g[nt] = Wa1f[258 * D + col];
        b1[nt] = ba1f[col]; wa2[nt] = Wa2f[col];
        t2d[nt] = We1f[128 * D + col]; t2a[nt] = We1f[129 * D + col]; t2g[nt] = We1f[130 * D + col];
        b2[nt] = be1f[col]; b3[nt] = be2f[col];
    }
    __syncthreads();

    // gather hr rows + build d = hc - hr (bf16) + geo
    {
        const int g = t >> 4;          // 16 groups of 16 threads, 4 edges each
#pragma unroll
        for (int it = 0; it < 4; ++it) {
            const int e = g * 4 + it;
            const int r = row_s[e], c = col_s[e];
            const uint4 vr = *(const uint4*)(hh1b + (size_t)r * D + l16 * 8);
            const uint4 vc = *(const uint4*)(hh1b + (size_t)c * D + l16 * 8);
            *(uint4*)&hr_s[e][l16 * 8] = vr;
            const unsigned* pr = (const unsigned*)&vr;
            const unsigned* pc = (const unsigned*)&vc;
            float s = 0.f; unsigned dw[4];
#pragma unroll
            for (int q = 0; q < 4; ++q) {
                const float r0 = __uint_as_float(pr[q] << 16), r1 = __uint_as_float(pr[q] & 0xffff0000u);
                const float c0 = __uint_as_float(pc[q] << 16), c1 = __uint_as_float(pc[q] & 0xffff0000u);
                const float d0 = c0 - r0, d1 = c1 - r1;
                s += d0 * d0 + d1 * d1;
                dw[q] = (unsigned)f2bs(d0) | ((unsigned)f2bs(d1) << 16);
            }
            *(uint4*)&d_s[e][l16 * 8] = make_uint4(dw[0], dw[1], dw[2], dw[3]);
            s += __shfl_xor(s, 1); s += __shfl_xor(s, 2); s += __shfl_xor(s, 4); s += __shfl_xor(s, 8);
            if (l16 == 0) {
                const float gg = sqrtf(s + 1e-8f);
                geo_s[e] = gg;
                if (base + e < E) e3buf[base + e] = make_float2(dist_s[e], gg);
            }
        }
    }
    __syncthreads();

    // ---- GEMM1: a1 = silu(hr@(Wr+Wc) + d@Wc + e3-tail + ba1) ; att partials ----
    f32x4 acc[2][4] = {};
    {
        const short8* pB = (const short8*)pWa1;
#pragma unroll
        for (int ks = 0; ks < 8; ++ks) {
            short8 bfr[4];
#pragma unroll
            for (int nt = 0; nt < 4; ++nt) bfr[nt] = pB[(ks * 8 + nh * 4 + nt) * 64 + lane];
#pragma unroll
            for (int mt = 0; mt < 2; ++mt) {
                const int row = mh * 32 + mt * 16 + l16;
                const short8 a = (ks < 4)
                    ? *(const short8*)&hr_s[row][ks * 32 + quad * 8]
                    : *(const short8*)&d_s[row][(ks - 4) * 32 + quad * 8];
#pragma unroll
                for (int nt = 0; nt < 4; ++nt) acc[mt][nt] = MFMA16(a, bfr[nt], acc[mt][nt]);
            }
        }
    }
    {
        float ap[2][4];
#pragma unroll
        for (int mt = 0; mt < 2; ++mt)
#pragma unroll
            for (int reg = 0; reg < 4; ++reg) {
                const int row = mh * 32 + mt * 16 + quad * 4 + reg;
                const float dd = dist_s[row], aa = attr_s[row], gg = geo_s[row];
                float p = 0.f;
#pragma unroll
                for (int nt = 0; nt < 4; ++nt) {
                    const float a1 = acc[mt][nt][reg] + b1[nt] + dd * t1d[nt] + aa * t1a[nt] + gg * t1g[nt];
                    p += siluf(a1) * wa2[nt];
                }
                float v = p;
                v += __shfl_xor(v, 1); v += __shfl_xor(v, 2); v += __shfl_xor(v, 4); v += __shfl_xor(v, 8);
                ap[mt][reg] = v;
            }
        if (l16 == 0) {
#pragma unroll
            for (int mt = 0; mt < 2; ++mt)
#pragma unroll
                for (int reg = 0; reg < 4; ++reg)
                    attp_s[nh][mh * 32 + mt * 16 + quad * 4 + reg] = ap[mt][reg];
        }
    }
    __syncthreads();   // (A) attp ready; hr_s reads complete -> overlay-writable

    if (t < TEB) {
        const float s = attp_s[0][t] + attp_s[1][t] + ba2f[0];
        att_s[t] = sigmf(s) * em_s[t];
    }

    // ---- GEMM2: m1 = silu(d@We1 + e3-tail + be1) -> bf16 into hr_s overlay ----
    {
        f32x4 acc2[2][4] = {};
        const short8* pB = (const short8*)pWe1;
#pragma unroll
        for (int ks = 0; ks < 4; ++ks) {
            short8 bfr[4];
#pragma unroll
            for (int nt = 0; nt < 4; ++nt) bfr[nt] = pB[(ks * 8 + nh * 4 + nt) * 64 + lane];
#pragma unroll
            for (int mt = 0; mt < 2; ++mt) {
                const short8 a = *(const short8*)&d_s[mh * 32 + mt * 16 + l16][ks * 32 + quad * 8];
#pragma unroll
                for (int nt = 0; nt < 4; ++nt) acc2[mt][nt] = MFMA16(a, bfr[nt], acc2[mt][nt]);
            }
        }
#pragma unroll
        for (int mt = 0; mt < 2; ++mt)
#pragma unroll
            for (int reg = 0; reg < 4; ++reg) {
                const int row = mh * 32 + mt * 16 + quad * 4 + reg;
                const float dd = dist_s[row], aa = attr_s[row], gg = geo_s[row];
#pragma unroll
                for (int nt = 0; nt < 4; ++nt) {
                    const float m1 = acc2[mt][nt][reg] + b2[nt] + dd * t2d[nt] + aa * t2a[nt] + gg * t2g[nt];
                    hr_s[row][nh * 64 + nt * 16 + l16] = f2bs(siluf(m1));
                }
            }
    }
    __syncthreads();   // (C) m1 + att complete

    // ---- GEMM3: msg = (m1@We2 + be2) * att ; atomicAdd into agg ----
    {
        f32x4 acc3[2][4] = {};
        const short8* pB = (const short8*)pWe2;
#pragma unroll
        for (int ks = 0; ks < 4; ++ks) {
            short8 bfr[4];
#pragma unroll
            for (int nt = 0; nt < 4; ++nt) bfr[nt] = pB[(ks * 8 + nh * 4 + nt) * 64 + lane];
#pragma unroll
            for (int mt = 0; mt < 2; ++mt) {
                const short8 a = *(const short8*)&hr_s[mh * 32 + mt * 16 + l16][ks * 32 + quad * 8];
#pragma unroll
                for (int nt = 0; nt < 4; ++nt) acc3[mt][nt] = MFMA16(a, bfr[nt], acc3[mt][nt]);
            }
        }
#pragma unroll
        for (int mt = 0; mt < 2; ++mt)
#pragma unroll
            for (int reg = 0; reg < 4; ++reg) {
                const int row = mh * 32 + mt * 16 + quad * 4 + reg;
                const float av = att_s[row];
                const size_t rb = (size_t)row_s[row] * D;
#pragma unroll
                for (int nt = 0; nt < 4; ++nt)
                    atomicAdd(&agg[rb + nh * 64 + nt * 16 + l16],
                              (acc3[mt][nt][reg] + b3[nt]) * av);
            }
    }
}

// ---------------- node MLP + residual + LayerNorm + silu ----------------
__global__ __launch_bounds__(128) void k_node2(
    const float* __restrict__ agg, const float* __restrict__ hh,
    const float* __restrict__ Wn1, const float* __restrict__ bn1,
    const float* __restrict__ Wn2, const float* __restrict__ bn2,
    const float* __restrict__ ln_g, const float* __restrict__ ln_b,
    float* __restrict__ out_h, ushort* __restrict__ hh2b) {
    const int i = blockIdx.x, j = threadIdx.x;
    __shared__ alignas(16) float ag[D];
    __shared__ alignas(16) float t1[D];
    __shared__ float red[D];
    ag[j] = agg[i * D + j];
    const float hv = hh[i * D + j];
    __syncthreads();

    float acc = bn1[j];
#pragma unroll 4
    for (int k = 0; k < D; k += 4) {
        const float4 v = *(const float4*)&ag[k];
        acc += v.x * Wn1[(k + 0) * D + j];
        acc += v.y * Wn1[(k + 1) * D + j];
        acc += v.z * Wn1[(k + 2) * D + j];
        acc += v.w * Wn1[(k + 3) * D + j];
    }
    t1[j] = siluf(acc);
    __syncthreads();

    acc = bn2[j];
#pragma unroll 4
    for (int k = 0; k < D; k += 4) {
        const float4 v = *(const float4*)&t1[k];
        acc += v.x * Wn2[(k + 0) * D + j];
        acc += v.y * Wn2[(k + 1) * D + j];
        acc += v.z * Wn2[(k + 2) * D + j];
        acc += v.w * Wn2[(k + 3) * D + j];
    }
    const float v = hv + acc;

    red[j] = v;
    __syncthreads();
    for (int s = 64; s > 0; s >>= 1) {
        if (j < s) red[j] += red[j + s];
        __syncthreads();
    }
    const float mu = red[0] * (1.0f / D);
    __syncthreads();
    const float dv = v - mu;
    red[j] = dv * dv;
    __syncthreads();
    for (int s = 64; s > 0; s >>= 1) {
        if (j < s) red[j] += red[j + s];
        __syncthreads();
    }
    const float var = red[0] * (1.0f / D);

    const float hn = dv * rsqrtf(var + 1e-5f) * ln_g[j] + ln_b[j];
    const float o = siluf(hn);
    out_h[i * D + j] = o;
    hh2b[i * D + j] = f2bs(o);
}

// ---------------- edge phase 2: coord MLP -> aggx (MFMA) ----------------
__global__ __launch_bounds__(256) void k_edge2(
    const int* __restrict__ eidx, const float* __restrict__ x,
    const float* __restrict__ eattr, const float* __restrict__ emask,
    const ushort* __restrict__ hh2b,
    const ushort* __restrict__ pWc1, const ushort* __restrict__ pWc2,
    const float* __restrict__ Wc1f, const float* __restrict__ bc1f,
    const float* __restrict__ bc2f, const float* __restrict__ Wc3f,
    const float2* __restrict__ e3buf, float* __restrict__ aggx, int E) {
    __shared__ ushort ar_s[TEB][RS];   // h2[row]; c1 overlay
    __shared__ ushort ac_s[TEB][RS];   // h2[col]
    __shared__ float dist_s[TEB], attr_s[TEB], geo_s[TEB], em_s[TEB];
    __shared__ float cdx_s[TEB], cdy_s[TEB], cdz_s[TEB];
    __shared__ int row_s[TEB], col_s[TEB];
    __shared__ float mp_s[2][TEB];

    const int t = threadIdx.x;
    const int lane = t & 63, wave = t >> 6;
    const int quad = lane >> 4, l16 = lane & 15;
    const int mh = wave >> 1, nh = wave & 1;
    const int base = blockIdx.x * TEB;

    if (t < TEB) {
        const int e = base + t;
        int r = 0, c = 0;
        float dist = 1.f, geo = 0.f, at = 0.f, em = 0.f, cdx = 0.f, cdy = 0.f, cdz = 0.f;
        if (e < E) {
            r = eidx[e]; c = eidx[E + e];
            const float2 dg = e3buf[e];
            dist = dg.x; geo = dg.y;
            at = eattr[e]; em = emask[e];
            const float inv = 1.0f / (dist + 1.0f);
            cdx = (x[r * 3 + 0] - x[c * 3 + 0]) * inv;
            cdy = (x[r * 3 + 1] - x[c * 3 + 1]) * inv;
            cdz = (x[r * 3 + 2] - x[c * 3 + 2]) * inv;
        }
        row_s[t] = r; col_s[t] = c;
        dist_s[t] = dist; geo_s[t] = geo; attr_s[t] = at; em_s[t] = em;
        cdx_s[t] = cdx; cdy_s[t] = cdy; cdz_s[t] = cdz;
    }
    float t1d[4], t1a[4], t1g[4], b1[4], b2[4], wc3[4];
#pragma unroll
    for (int nt = 0; nt < 4; ++nt) {
        const int col = nh * 64 + nt * 16 + l16;
        t1d[nt] = Wc1f[256 * D + col]; t1a[nt] = Wc1f[257 * D + col]; t1g[nt] = Wc1f[258 * D + col];
        b1[nt] = bc1f[col]; b2[nt] = bc2f[col]; wc3[nt] = Wc3f[col];
    }
    __syncthreads();

    {
        const int g = t >> 4;
#pragma unroll
        for (int it = 0; it < 4; ++it) {
            const int e = g * 4 + it;
            *(uint4*)&ar_s[e][l16 * 8] = *(const uint4*)(hh2b + (size_t)row_s[e] * D + l16 * 8);
            *(uint4*)&ac_s[e][l16 * 8] = *(const uint4*)(hh2b + (size_t)col_s[e] * D + l16 * 8);
        }
    }
    __syncthreads();

    // ---- GEMM1: c1 = silu([h2r|h2c]@Wc1 + e3-tail + bc1) ----
    f32x4 acc[2][4] = {};
    {
        const short8* pB = (const short8*)pWc1;
#pragma unroll
        for (int ks = 0; ks < 8; ++ks) {
            short8 bfr[4];
#pragma unroll
            for (int nt = 0; nt < 4; ++nt) bfr[nt] = pB[(ks * 8 + nh * 4 + nt) * 64 + lane];
#pragma unroll
            for (int mt = 0; mt < 2; ++mt) {
                const int row = mh * 32 + mt * 16 + l16;
                const short8 a = (ks < 4)
                    ? *(const short8*)&ar_s[row][ks * 32 + quad * 8]
                    : *(const short8*)&ac_s[row][(ks - 4) * 32 + quad * 8];
#pragma unroll
                for (int nt = 0; nt < 4; ++nt) acc[mt][nt] = MFMA16(a, bfr[nt], acc[mt][nt]);
            }
        }
    }
#pragma unroll
    for (int mt = 0; mt < 2; ++mt)
#pragma unroll
        for (int reg = 0; reg < 4; ++reg) {
            const int row = mh * 32 + mt * 16 + quad * 4 + reg;
            const float dd = dist_s[row], aa = attr_s[row], gg = geo_s[row];
#pragma unroll
            for (int nt = 0; nt < 4; ++nt)
                acc[mt][nt][reg] = siluf(acc[mt][nt][reg] + b1[nt] + dd * t1d[nt] + aa * t1a[nt] + gg * t1g[nt]);
        }
    __syncthreads();   // all GEMM1 reads done -> c1 overlay into ar_s
#pragma unroll
    for (int mt = 0; mt < 2; ++mt)
#pragma unroll
        for (int reg = 0; reg < 4; ++reg) {
            const int row = mh * 32 + mt * 16 + quad * 4 + reg;
#pragma unroll
            for (int nt = 0; nt < 4; ++nt)
                ar_s[row][nh * 64 + nt * 16 + l16] = f2bs(acc[mt][nt][reg]);
        }
    __syncthreads();

    // ---- GEMM2: c2 = silu(c1@Wc2 + bc2) ; m = c2 . Wc3 (row-dot) ----
    {
        f32x4 acc2[2][4] = {};
        const short8* pB = (const short8*)pWc2;
#pragma unroll
        for (int ks = 0; ks < 4; ++ks) {
            short8 bfr[4];
#pragma unroll
            for (int nt = 0; nt < 4; ++nt) bfr[nt] = pB[(ks * 8 + nh * 4 + nt) * 64 + lane];
#pragma unroll
            for (int mt = 0; mt < 2; ++mt) {
                const short8 a = *(const short8*)&ar_s[mh * 32 + mt * 16 + l16][ks * 32 + quad * 8];
#pragma unroll
                for (int nt = 0; nt < 4; ++nt) acc2[mt][nt] = MFMA16(a, bfr[nt], acc2[mt][nt]);
            }
        }
#pragma unroll
        for (int mt = 0; mt < 2; ++mt)
#pragma unroll
            for (int reg = 0; reg < 4; ++reg) {
                float p = 0.f;
#pragma unroll
                for (int nt = 0; nt < 4; ++nt)
                    p += siluf(acc2[mt][nt][reg] + b2[nt]) * wc3[nt];
                p += __shfl_xor(p, 1); p += __shfl_xor(p, 2); p += __shfl_xor(p, 4); p += __shfl_xor(p, 8);
                if (l16 == 0) mp_s[nh][mh * 32 + mt * 16 + quad * 4 + reg] = p;
            }
    }
    __syncthreads();

    if (t < TEB) {
        const float m = mp_s[0][t] + mp_s[1][t];
        const float tr = m * em_s[t];
        const int r4 = row_s[t] * 4;
        atomicAdd(&aggx[r4 + 0], cdx_s[t] * tr);
        atomicAdd(&aggx[r4 + 1], cdy_s[t] * tr);
        atomicAdd(&aggx[r4 + 2], cdz_s[t] * tr);
    }
}

// ---------------- coord epilogue ----------------
__global__ void k_coord(const float* __restrict__ x, const float* __restrict__ nmask,
                        const float* __restrict__ aggx, float* __restrict__ out_x, int N) {
    const int idx = blockIdx.x * blockDim.x + threadIdx.x;
    if (idx >= N * 3) return;
    const int i = idx / 3, d = idx - i * 3;
    out_x[idx] = (x[idx] + aggx[i * 4 + d] * (1.0f / 100.0f)) * nmask[i];
}

extern "C" void kernel_launch(void* const* d_in, const int* in_sizes, int n_in,
                              void* d_out, int out_size, void* d_ws, size_t ws_size,
                              hipStream_t stream) {
    const float* h     = (const float*)d_in[0];
    const float* x     = (const float*)d_in[1];
    const int*   eidx  = (const int*)d_in[2];
    const float* nmask = (const float*)d_in[3];
    const float* emask = (const float*)d_in[4];
    const float* eattr = (const float*)d_in[5];
    const float* W_lin = (const float*)d_in[6];
    const float* b_lin = (const float*)d_in[7];
    const float* We1   = (const float*)d_in[8];
    const float* be1   = (const float*)d_in[9];
    const float* We2   = (const float*)d_in[10];
    const float* be2   = (const float*)d_in[11];
    const float* Wn1   = (const float*)d_in[12];
    const float* bn1   = (const float*)d_in[13];
    const float* Wn2   = (const float*)d_in[14];
    const float* bn2   = (const float*)d_in[15];
    const float* Wa1   = (const float*)d_in[16];
    const float* ba1   = (const float*)d_in[17];
    const float* Wa2   = (const float*)d_in[18];
    const float* ba2   = (const float*)d_in[19];
    const float* ln_g  = (const float*)d_in[20];
    const float* ln_b  = (const float*)d_in[21];
    const float* Wc1   = (const float*)d_in[22];
    const float* bc1   = (const float*)d_in[23];
    const float* Wc2   = (const float*)d_in[24];
    const float* bc2   = (const float*)d_in[25];
    const float* Wc3   = (const float*)d_in[26];

    const int N = in_sizes[0] / D;
    const int E = in_sizes[2] / 2;

    // ws: hh_f32 | agg | aggx | e3buf | hh1b | hh2b | packed weights (~36.5 MB)
    float*  hh    = (float*)d_ws;
    float*  agg   = hh + (size_t)N * D;
    float*  aggx  = agg + (size_t)N * D;
    float2* e3buf = (float2*)(aggx + (size_t)N * 4);
    ushort* hh1b  = (ushort*)(e3buf + (size_t)E);
    ushort* hh2b  = hh1b + (size_t)N * D;
    ushort* pWa1  = hh2b + (size_t)N * D;
    ushort* pWe1  = pWa1 + 32768;
    ushort* pWe2  = pWe1 + 16384;
    ushort* pWc1  = pWe2 + 16384;
    ushort* pWc2  = pWc1 + 32768;

    float* out_h = (float*)d_out;
    float* out_x = out_h + (size_t)N * D;

    const int EB = (E + TEB - 1) / TEB;

    k_zero<<<2048, 256, 0, stream>>>(agg, (long)N * D + (long)N * 4);
    k_pack<<<128, 256, 0, stream>>>(Wa1, pWa1, 8, 1);   // folded [hr|d] weights
    k_pack<<< 64, 256, 0, stream>>>(We1, pWe1, 4, 0);
    k_pack<<< 64, 256, 0, stream>>>(We2, pWe2, 4, 0);
    k_pack<<<128, 256, 0, stream>>>(Wc1, pWc1, 8, 0);
    k_pack<<< 64, 256, 0, stream>>>(Wc2, pWc2, 4, 0);

    k_node_lin<<<N, 128, 0, stream>>>(h, W_lin, b_lin, hh, hh1b);
    k_edge1<<<EB, 256, 0, stream>>>(eidx, x, eattr, emask, hh1b,
                                    pWa1, pWe1, pWe2,
                                    Wa1, ba1, Wa2, ba2, We1, be1, be2,
                                    agg, e3buf, E);
    k_node2<<<N, 128, 0, stream>>>(agg, hh, Wn1, bn1, Wn2, bn2, ln_g, ln_b, out_h, hh2b);
    k_edge2<<<EB, 256, 0, stream>>>(eidx, x, eattr, emask, hh2b,
                                    pWc1, pWc2, Wc1, bc1, bc2, Wc3,
                                    e3buf, aggx, E);
    k_coord<<<(N * 3 + 255) / 256, 256, 0, stream>>>(x, nmask, aggx, out_x, N);
}

// Round 5
// 591.343 us; speedup vs baseline: 6.2881x; 1.1803x over previous
//
#include <hip/hip_runtime.h>
#include <hip/hip_bf16.h>

// EquivariantBlock — Round 5.
// R4: k_edge1 MfmaUtil 12 / VALU 47 / occ 32% -> concurrency-bound, not pipe-bound.
// Changes: TEB 64->32 + waves-as-col-quarters (LDS 37->19KB -> 6-8 blocks/CU);
// e3 tail + biases folded into MFMA as a 9th K-step (A-ext=[dist,attr,geo,1]);
// node_lin/node2 MFMA-ized (64-node blocks, LN via shuffles); one fused pack kernel.

#define D 128
#define RS 136          // LDS row stride in bf16 units (128 + 8 pad)

typedef unsigned short ushort;
typedef __attribute__((ext_vector_type(8))) short short8;
typedef __attribute__((ext_vector_type(4))) float f32x4;

__device__ __forceinline__ float siluf(float x) { return x / (1.0f + __expf(-x)); }
__device__ __forceinline__ float sigmf(float x) { return 1.0f / (1.0f + __expf(-x)); }
__device__ __forceinline__ ushort f2bs(float f) {
    __hip_bfloat16 b = __float2bfloat16(f);
    ushort u; __builtin_memcpy(&u, &b, 2); return u;
}
__device__ __forceinline__ unsigned pkbf(float lo, float hi) {
    __hip_bfloat162 h2 = __float22bfloat162_rn(make_float2(lo, hi));
    unsigned u; __builtin_memcpy(&u, &h2, 4); return u;
}
#define MFMA16(a, b, c) __builtin_amdgcn_mfma_f32_16x16x32_bf16((a), (b), (c), 0, 0, 0)

// packed-weight block offsets (units of 4096 ushorts = one ks-block)
#define PWLIN 0
#define PWA1  5
#define PWE1  14
#define PWE2  19
#define PWN1  23
#define PWN2  28
#define PWC1  32
#define PWC2  41
#define NPACK 45

// ---------------- zero scratch ----------------
__global__ void k_zero(float* __restrict__ p, long n) {
    long i = (long)blockIdx.x * blockDim.x + threadIdx.x;
    long stride = (long)gridDim.x * blockDim.x;
    for (; i < n; i += stride) p[i] = 0.0f;
}

// ---------------- fused weight pack: 45 ks-blocks, one launch ----------------
// normal block: dst[e] = W[(kbase + klocal)*D + n] (+fold row+128)
// ext block: klocal<nW -> W[(kbase+klocal)*D+n]; klocal==nW -> bias[n]; else 0
__global__ __launch_bounds__(256) void k_packall(
    const float* __restrict__ W_lin, const float* __restrict__ b_lin,
    const float* __restrict__ Wa1, const float* __restrict__ ba1,
    const float* __restrict__ We1, const float* __restrict__ be1,
    const float* __restrict__ We2,
    const float* __restrict__ Wn1, const float* __restrict__ bn1,
    const float* __restrict__ Wn2,
    const float* __restrict__ Wc1, const float* __restrict__ bc1,
    const float* __restrict__ Wc2,
    ushort* __restrict__ pack) {
    const int b = blockIdx.x, t = threadIdx.x;
    const float* W = nullptr; const float* bias = nullptr;
    int kbase = 0, fold = 0, ext = 0, nW = 0;
    if (b < 5)       { W = W_lin; bias = b_lin; if (b == 4) { ext = 1; nW = 0; } else kbase = b * 32; }
    else if (b < 14) { int k = b - 5;  W = Wa1; bias = ba1; if (k == 8) { ext = 1; nW = 3; kbase = 256; } else { kbase = k * 32; fold = (k < 4); } }
    else if (b < 19) { int k = b - 14; W = We1; bias = be1; if (k == 4) { ext = 1; nW = 3; kbase = 128; } else kbase = k * 32; }
    else if (b < 23) { W = We2; kbase = (b - 19) * 32; }
    else if (b < 28) { int k = b - 23; W = Wn1; bias = bn1; if (k == 4) { ext = 1; nW = 0; } else kbase = k * 32; }
    else if (b < 32) { W = Wn2; kbase = (b - 28) * 32; }
    else if (b < 41) { int k = b - 32; W = Wc1; bias = bc1; if (k == 8) { ext = 1; nW = 3; kbase = 256; } else kbase = k * 32; }
    else             { W = Wc2; kbase = (b - 41) * 32; }
    ushort* dst = pack + (size_t)b * 4096;
#pragma unroll
    for (int i = 0; i < 16; ++i) {
        const int e = t + 256 * i;
        const int j = e & 7, lane = (e >> 3) & 63, nt = e >> 9;
        const int kl = (lane >> 4) * 8 + j;
        const int n = nt * 16 + (lane & 15);
        float v;
        if (!ext) {
            v = W[(kbase + kl) * D + n];
            if (fold) v += W[(kbase + kl + 128) * D + n];
        } else {
            v = (kl < nW) ? W[(kbase + kl) * D + n] : (kl == nW ? bias[n] : 0.0f);
        }
        dst[e] = f2bs(v);
    }
}

// ---------------- node_lin: hh = h @ W_lin + b (MFMA, 64 nodes/block) ----------------
__global__ __launch_bounds__(256) void k_node_lin(
    const float* __restrict__ h, const ushort* __restrict__ pack,
    float* __restrict__ hh, ushort* __restrict__ hh1b, int N) {
    __shared__ ushort hs[64][RS];
    const int t = threadIdx.x, lane = t & 63, wave = t >> 6;
    const int quad = lane >> 4, l16 = lane & 15;
    const int mh = wave >> 1, nh = wave & 1;
    const int base = blockIdx.x * 64;

    // stage h fp32 -> bf16 LDS (coalesced), clamp OOB rows
#pragma unroll
    for (int q = 0; q < 8; ++q) {
        const int f = t + 256 * q;
        const int row = f >> 5, c4 = (f & 31) << 2;
        const int node = base + row;
        float4 v = make_float4(0.f, 0.f, 0.f, 0.f);
        if (node < N) v = *(const float4*)(h + (size_t)node * D + c4);
        *(uint2*)&hs[row][c4] = make_uint2(pkbf(v.x, v.y), pkbf(v.z, v.w));
    }
    __syncthreads();

    short8 aext = (short8)0;
    if (quad == 0) aext[0] = (short)0x3F80;   // ones column -> bias row

    f32x4 acc[2][4] = {};
    const short8* pB = (const short8*)(pack + (size_t)PWLIN * 4096);
#pragma unroll
    for (int ks = 0; ks < 5; ++ks) {
        short8 bfr[4];
#pragma unroll
        for (int nt = 0; nt < 4; ++nt) bfr[nt] = pB[(ks * 8 + nh * 4 + nt) * 64 + lane];
#pragma unroll
        for (int mt = 0; mt < 2; ++mt) {
            const short8 a = (ks < 4) ? *(const short8*)&hs[mh * 32 + mt * 16 + l16][ks * 32 + quad * 8]
                                      : aext;
#pragma unroll
            for (int nt = 0; nt < 4; ++nt) acc[mt][nt] = MFMA16(a, bfr[nt], acc[mt][nt]);
        }
    }
#pragma unroll
    for (int mt = 0; mt < 2; ++mt)
#pragma unroll
        for (int reg = 0; reg < 4; ++reg) {
            const int g = base + mh * 32 + mt * 16 + quad * 4 + reg;
            if (g < N) {
#pragma unroll
                for (int nt = 0; nt < 4; ++nt) {
                    const int col = nh * 64 + nt * 16 + l16;
                    const float v = acc[mt][nt][reg];
                    hh[(size_t)g * D + col] = v;
                    hh1b[(size_t)g * D + col] = f2bs(v);
                }
            }
        }
}

// ---------------- edge phase 1: att + msg -> agg (MFMA, 32 edges/block) ----------------
__global__ __launch_bounds__(256) void k_edge1(
    const int* __restrict__ eidx, const float* __restrict__ x,
    const float* __restrict__ eattr, const float* __restrict__ emask,
    const ushort* __restrict__ hh1b, const ushort* __restrict__ pack,
    const float* __restrict__ Wa2f, const float* __restrict__ ba2f,
    const float* __restrict__ be2f,
    float* __restrict__ agg, float2* __restrict__ e3buf, int E) {
    __shared__ ushort hr_s[32][RS];   // hr; m1 overlay for GEMM3
    __shared__ ushort d_s[32][RS];    // hc - hr
    __shared__ float dist_s[32], attr_s[32], geo_s[32], att_s[32], em_s[32];
    __shared__ int row_s[32], col_s[32];
    __shared__ float attp_s[4][32];

    const int t = threadIdx.x, lane = t & 63, w = t >> 6;
    const int quad = lane >> 4, l16 = lane & 15;
    const int base = blockIdx.x * 32;

    if (t < 32) {
        const int e = base + t;
        int r = 0, c = 0; float dist = 0.f, at = 0.f, em = 0.f;
        if (e < E) {
            r = eidx[e]; c = eidx[E + e];
            const float dx = x[r * 3 + 0] - x[c * 3 + 0];
            const float dy = x[r * 3 + 1] - x[c * 3 + 1];
            const float dz = x[r * 3 + 2] - x[c * 3 + 2];
            dist = sqrtf(dx * dx + dy * dy + dz * dz + 1e-8f);
            at = eattr[e]; em = emask[e];
        }
        row_s[t] = r; col_s[t] = c;
        dist_s[t] = dist; attr_s[t] = at; em_s[t] = em;
    }
    float wa2[2], b3[2];
#pragma unroll
    for (int nt = 0; nt < 2; ++nt) {
        const int col = w * 32 + nt * 16 + l16;
        wa2[nt] = Wa2f[col]; b3[nt] = be2f[col];
    }
    __syncthreads();

    // gather: 16 groups of 16 lanes, 2 edges each; build hr, d=hc-hr, geo
    {
        const int g = t >> 4;
#pragma unroll
        for (int it = 0; it < 2; ++it) {
            const int e = g * 2 + it;
            const uint4 vr = *(const uint4*)(hh1b + (size_t)row_s[e] * D + l16 * 8);
            const uint4 vc = *(const uint4*)(hh1b + (size_t)col_s[e] * D + l16 * 8);
            *(uint4*)&hr_s[e][l16 * 8] = vr;
            const unsigned* pr = (const unsigned*)&vr;
            const unsigned* pc = (const unsigned*)&vc;
            float s = 0.f; unsigned dw[4];
#pragma unroll
            for (int q = 0; q < 4; ++q) {
                const float r0 = __uint_as_float(pr[q] << 16), r1 = __uint_as_float(pr[q] & 0xffff0000u);
                const float c0 = __uint_as_float(pc[q] << 16), c1 = __uint_as_float(pc[q] & 0xffff0000u);
                const float d0 = c0 - r0, d1 = c1 - r1;
                s += d0 * d0 + d1 * d1;
                dw[q] = pkbf(d0, d1);
            }
            *(uint4*)&d_s[e][l16 * 8] = make_uint4(dw[0], dw[1], dw[2], dw[3]);
            s += __shfl_xor(s, 1); s += __shfl_xor(s, 2); s += __shfl_xor(s, 4); s += __shfl_xor(s, 8);
            if (l16 == 0) {
                const float gg = sqrtf(s + 1e-8f);
                geo_s[e] = gg;
                if (base + e < E) e3buf[base + e] = make_float2(dist_s[e], gg);
            }
        }
    }
    __syncthreads();

    // e3+bias extension A-fragments (per 16-edge half)
    short8 aext[2];
#pragma unroll
    for (int mt = 0; mt < 2; ++mt) {
        short8 v = (short8)0;
        if (quad == 0) {
            const int m = mt * 16 + l16;
            v[0] = (short)f2bs(dist_s[m]); v[1] = (short)f2bs(attr_s[m]);
            v[2] = (short)f2bs(geo_s[m]);  v[3] = (short)0x3F80;
        }
        aext[mt] = v;
    }

    // GEMM1: a1 = silu(hr@(Wr+Wc) + d@Wc + ext)  (wave: 32 edges x 32 cols)
    {
        f32x4 acc[2][2] = {};
        const short8* pB = (const short8*)(pack + (size_t)PWA1 * 4096);
#pragma unroll
        for (int ks = 0; ks < 9; ++ks) {
            short8 b0 = pB[(ks * 8 + w * 2 + 0) * 64 + lane];
            short8 b1 = pB[(ks * 8 + w * 2 + 1) * 64 + lane];
#pragma unroll
            for (int mt = 0; mt < 2; ++mt) {
                const short8 a = (ks < 4) ? *(const short8*)&hr_s[mt * 16 + l16][ks * 32 + quad * 8]
                               : (ks < 8) ? *(const short8*)&d_s[mt * 16 + l16][(ks - 4) * 32 + quad * 8]
                                          : aext[mt];
                acc[mt][0] = MFMA16(a, b0, acc[mt][0]);
                acc[mt][1] = MFMA16(a, b1, acc[mt][1]);
            }
        }
        // att partial: sum over this wave's 32 cols of silu(a1)*wa2
#pragma unroll
        for (int mt = 0; mt < 2; ++mt)
#pragma unroll
            for (int reg = 0; reg < 4; ++reg) {
                float p = siluf(acc[mt][0][reg]) * wa2[0] + siluf(acc[mt][1][reg]) * wa2[1];
                p += __shfl_xor(p, 1); p += __shfl_xor(p, 2); p += __shfl_xor(p, 4); p += __shfl_xor(p, 8);
                if (l16 == 0) attp_s[w][mt * 16 + quad * 4 + reg] = p;
            }
    }
    __syncthreads();   // attp ready; all GEMM1 LDS reads done

    if (t < 32)
        att_s[t] = sigmf(attp_s[0][t] + attp_s[1][t] + attp_s[2][t] + attp_s[3][t] + ba2f[0]) * em_s[t];

    // GEMM2: m1 = silu(d@We1 + ext) -> bf16 overlay into hr_s
    {
        f32x4 acc[2][2] = {};
        const short8* pB = (const short8*)(pack + (size_t)PWE1 * 4096);
#pragma unroll
        for (int ks = 0; ks < 5; ++ks) {
            short8 b0 = pB[(ks * 8 + w * 2 + 0) * 64 + lane];
            short8 b1 = pB[(ks * 8 + w * 2 + 1) * 64 + lane];
#pragma unroll
            for (int mt = 0; mt < 2; ++mt) {
                const short8 a = (ks < 4) ? *(const short8*)&d_s[mt * 16 + l16][ks * 32 + quad * 8]
                                          : aext[mt];
                acc[mt][0] = MFMA16(a, b0, acc[mt][0]);
                acc[mt][1] = MFMA16(a, b1, acc[mt][1]);
            }
        }
#pragma unroll
        for (int mt = 0; mt < 2; ++mt)
#pragma unroll
            for (int reg = 0; reg < 4; ++reg) {
                const int row = mt * 16 + quad * 4 + reg;
#pragma unroll
                for (int nt = 0; nt < 2; ++nt)
                    hr_s[row][w * 32 + nt * 16 + l16] = f2bs(siluf(acc[mt][nt][reg]));
            }
    }
    __syncthreads();   // m1 + att ready

    // GEMM3: msg = (m1@We2 + be2) * att ; atomicAdd into agg
    {
        f32x4 acc[2][2] = {};
        const short8* pB = (const short8*)(pack + (size_t)PWE2 * 4096);
#pragma unroll
        for (int ks = 0; ks < 4; ++ks) {
            short8 b0 = pB[(ks * 8 + w * 2 + 0) * 64 + lane];
            short8 b1 = pB[(ks * 8 + w * 2 + 1) * 64 + lane];
#pragma unroll
            for (int mt = 0; mt < 2; ++mt) {
                const short8 a = *(const short8*)&hr_s[mt * 16 + l16][ks * 32 + quad * 8];
                acc[mt][0] = MFMA16(a, b0, acc[mt][0]);
                acc[mt][1] = MFMA16(a, b1, acc[mt][1]);
            }
        }
#pragma unroll
        for (int mt = 0; mt < 2; ++mt)
#pragma unroll
            for (int reg = 0; reg < 4; ++reg) {
                const int row = mt * 16 + quad * 4 + reg;
                const float av = att_s[row];
                const size_t rb = (size_t)row_s[row] * D;
#pragma unroll
                for (int nt = 0; nt < 2; ++nt)
                    atomicAdd(&agg[rb + w * 32 + nt * 16 + l16], (acc[mt][nt][reg] + b3[nt]) * av);
            }
    }
}

// ---------------- node2: MLP + residual + LN + silu (MFMA, 64 nodes/block) ----------------
__global__ __launch_bounds__(256) void k_node2(
    const float* __restrict__ agg, const float* __restrict__ hh,
    const ushort* __restrict__ pack,
    const float* __restrict__ bn2f,
    const float* __restrict__ ln_g, const float* __restrict__ ln_b,
    float* __restrict__ out_h, ushort* __restrict__ hh2b, int N) {
    __shared__ ushort ag_s[64][RS];   // agg bf16; t1 overlay
    __shared__ float redS[2][64], redQ[2][64];
    const int t = threadIdx.x, lane = t & 63, wave = t >> 6;
    const int quad = lane >> 4, l16 = lane & 15;
    const int mh = wave >> 1, nh = wave & 1;
    const int base = blockIdx.x * 64;

#pragma unroll
    for (int q = 0; q < 8; ++q) {
        const int f = t + 256 * q;
        const int row = f >> 5, c4 = (f & 31) << 2;
        const int node = base + row;
        float4 v = make_float4(0.f, 0.f, 0.f, 0.f);
        if (node < N) v = *(const float4*)(agg + (size_t)node * D + c4);
        *(uint2*)&ag_s[row][c4] = make_uint2(pkbf(v.x, v.y), pkbf(v.z, v.w));
    }
    float bn2[4], lg[4], lb[4];
#pragma unroll
    for (int nt = 0; nt < 4; ++nt) {
        const int col = nh * 64 + nt * 16 + l16;
        bn2[nt] = bn2f[col]; lg[nt] = ln_g[col]; lb[nt] = ln_b[col];
    }
    __syncthreads();

    short8 aext = (short8)0;
    if (quad == 0) aext[0] = (short)0x3F80;

    // GEMM1: t1 = silu(agg@Wn1 + bn1)
    f32x4 acc[2][4] = {};
    {
        const short8* pB = (const short8*)(pack + (size_t)PWN1 * 4096);
#pragma unroll
        for (int ks = 0; ks < 5; ++ks) {
            short8 bfr[4];
#pragma unroll
            for (int nt = 0; nt < 4; ++nt) bfr[nt] = pB[(ks * 8 + nh * 4 + nt) * 64 + lane];
#pragma unroll
            for (int mt = 0; mt < 2; ++mt) {
                const short8 a = (ks < 4) ? *(const short8*)&ag_s[mh * 32 + mt * 16 + l16][ks * 32 + quad * 8]
                                          : aext;
#pragma unroll
                for (int nt = 0; nt < 4; ++nt) acc[mt][nt] = MFMA16(a, bfr[nt], acc[mt][nt]);
            }
        }
    }
    __syncthreads();   // GEMM1 reads done -> overlay
#pragma unroll
    for (int mt = 0; mt < 2; ++mt)
#pragma unroll
        for (int reg = 0; reg < 4; ++reg) {
            const int row = mh * 32 + mt * 16 + quad * 4 + reg;
#pragma unroll
            for (int nt = 0; nt < 4; ++nt)
                ag_s[row][nh * 64 + nt * 16 + l16] = f2bs(siluf(acc[mt][nt][reg]));
        }
    __syncthreads();

    // GEMM2: v = t1@Wn2 + bn2 + hh  (residual), then LN stats
    {
        const short8* pB = (const short8*)(pack + (size_t)PWN2 * 4096);
#pragma unroll
        for (int mt = 0; mt < 2; ++mt)
#pragma unroll
            for (int nt = 0; nt < 4; ++nt) acc[mt][nt] = (f32x4)0.0f;
#pragma unroll
        for (int ks = 0; ks < 4; ++ks) {
            short8 bfr[4];
#pragma unroll
            for (int nt = 0; nt < 4; ++nt) bfr[nt] = pB[(ks * 8 + nh * 4 + nt) * 64 + lane];
#pragma unroll
            for (int mt = 0; mt < 2; ++mt) {
                const short8 a = *(const short8*)&ag_s[mh * 32 + mt * 16 + l16][ks * 32 + quad * 8];
#pragma unroll
                for (int nt = 0; nt < 4; ++nt) acc[mt][nt] = MFMA16(a, bfr[nt], acc[mt][nt]);
            }
        }
    }
#pragma unroll
    for (int mt = 0; mt < 2; ++mt)
#pragma unroll
        for (int reg = 0; reg < 4; ++reg) {
            const int row = mh * 32 + mt * 16 + quad * 4 + reg;
            const int g = base + row;
            float s = 0.f, qq = 0.f;
#pragma unroll
            for (int nt = 0; nt < 4; ++nt) {
                const int col = nh * 64 + nt * 16 + l16;
                float v = acc[mt][nt][reg] + bn2[nt];
                if (g < N) v += hh[(size_t)g * D + col];
                acc[mt][nt][reg] = v;
                s += v; qq += v * v;
            }
            s += __shfl_xor(s, 1); s += __shfl_xor(s, 2); s += __shfl_xor(s, 4); s += __shfl_xor(s, 8);
            qq += __shfl_xor(qq, 1); qq += __shfl_xor(qq, 2); qq += __shfl_xor(qq, 4); qq += __shfl_xor(qq, 8);
            if (l16 == 0) { redS[nh][row] = s; redQ[nh][row] = qq; }
        }
    __syncthreads();

#pragma unroll
    for (int mt = 0; mt < 2; ++mt)
#pragma unroll
        for (int reg = 0; reg < 4; ++reg) {
            const int row = mh * 32 + mt * 16 + quad * 4 + reg;
            const int g = base + row;
            const float mu = (redS[0][row] + redS[1][row]) * (1.0f / D);
            const float var = (redQ[0][row] + redQ[1][row]) * (1.0f / D) - mu * mu;
            const float rstd = rsqrtf(var + 1e-5f);
            if (g < N) {
#pragma unroll
                for (int nt = 0; nt < 4; ++nt) {
                    const int col = nh * 64 + nt * 16 + l16;
                    const float hn = (acc[mt][nt][reg] - mu) * rstd * lg[nt] + lb[nt];
                    const float o = siluf(hn);
                    out_h[(size_t)g * D + col] = o;
                    hh2b[(size_t)g * D + col] = f2bs(o);
                }
            }
        }
}

// ---------------- edge phase 2: coord MLP -> aggx (MFMA, 32 edges/block) ----------------
__global__ __launch_bounds__(256) void k_edge2(
    const int* __restrict__ eidx, const float* __restrict__ x,
    const float* __restrict__ eattr, const float* __restrict__ emask,
    const ushort* __restrict__ hh2b, const ushort* __restrict__ pack,
    const float* __restrict__ bc2f, const float* __restrict__ Wc3f,
    const float2* __restrict__ e3buf, float* __restrict__ aggx, int E) {
    __shared__ ushort ar_s[32][RS];   // h2[row]; c1 overlay
    __shared__ ushort ac_s[32][RS];   // h2[col]
    __shared__ float dist_s[32], attr_s[32], geo_s[32], em_s[32];
    __shared__ float cdx_s[32], cdy_s[32], cdz_s[32];
    __shared__ int row_s[32], col_s[32];
    __shared__ float mp_s[4][32];

    const int t = threadIdx.x, lane = t & 63, w = t >> 6;
    const int quad = lane >> 4, l16 = lane & 15;
    const int base = blockIdx.x * 32;

    if (t < 32) {
        const int e = base + t;
        int r = 0, c = 0;
        float dist = 1.f, geo = 0.f, at = 0.f, em = 0.f, cdx = 0.f, cdy = 0.f, cdz = 0.f;
        if (e < E) {
            r = eidx[e]; c = eidx[E + e];
            const float2 dg = e3buf[e];
            dist = dg.x; geo = dg.y;
            at = eattr[e]; em = emask[e];
            const float inv = 1.0f / (dist + 1.0f);
            cdx = (x[r * 3 + 0] - x[c * 3 + 0]) * inv;
            cdy = (x[r * 3 + 1] - x[c * 3 + 1]) * inv;
            cdz = (x[r * 3 + 2] - x[c * 3 + 2]) * inv;
        }
        row_s[t] = r; col_s[t] = c;
        dist_s[t] = dist; geo_s[t] = geo; attr_s[t] = at; em_s[t] = em;
        cdx_s[t] = cdx; cdy_s[t] = cdy; cdz_s[t] = cdz;
    }
    float bc2[2], wc3[2];
#pragma unroll
    for (int nt = 0; nt < 2; ++nt) {
        const int col = w * 32 + nt * 16 + l16;
        bc2[nt] = bc2f[col]; wc3[nt] = Wc3f[col];
    }
    __syncthreads();

    {
        const int g = t >> 4;
#pragma unroll
        for (int it = 0; it < 2; ++it) {
            const int e = g * 2 + it;
            *(uint4*)&ar_s[e][l16 * 8] = *(const uint4*)(hh2b + (size_t)row_s[e] * D + l16 * 8);
            *(uint4*)&ac_s[e][l16 * 8] = *(const uint4*)(hh2b + (size_t)col_s[e] * D + l16 * 8);
        }
    }
    __syncthreads();

    short8 aext[2];
#pragma unroll
    for (int mt = 0; mt < 2; ++mt) {
        short8 v = (short8)0;
        if (quad == 0) {
            const int m = mt * 16 + l16;
            v[0] = (short)f2bs(dist_s[m]); v[1] = (short)f2bs(attr_s[m]);
            v[2] = (short)f2bs(geo_s[m]);  v[3] = (short)0x3F80;
        }
        aext[mt] = v;
    }

    // GEMM1: c1 = silu([h2r|h2c]@Wc1 + ext)
    {
        f32x4 acc[2][2] = {};
        const short8* pB = (const short8*)(pack + (size_t)PWC1 * 4096);
#pragma unroll
        for (int ks = 0; ks < 9; ++ks) {
            short8 b0 = pB[(ks * 8 + w * 2 + 0) * 64 + lane];
            short8 b1 = pB[(ks * 8 + w * 2 + 1) * 64 + lane];
#pragma unroll
            for (int mt = 0; mt < 2; ++mt) {
                const short8 a = (ks < 4) ? *(const short8*)&ar_s[mt * 16 + l16][ks * 32 + quad * 8]
                               : (ks < 8) ? *(const short8*)&ac_s[mt * 16 + l16][(ks - 4) * 32 + quad * 8]
                                          : aext[mt];
                acc[mt][0] = MFMA16(a, b0, acc[mt][0]);
                acc[mt][1] = MFMA16(a, b1, acc[mt][1]);
            }
        }
        __syncthreads();   // GEMM1 reads done -> c1 overlay
#pragma unroll
        for (int mt = 0; mt < 2; ++mt)
#pragma unroll
            for (int reg = 0; reg < 4; ++reg) {
                const int row = mt * 16 + quad * 4 + reg;
#pragma unroll
                for (int nt = 0; nt < 2; ++nt)
                    ar_s[row][w * 32 + nt * 16 + l16] = f2bs(siluf(acc[mt][nt][reg]));
            }
    }
    __syncthreads();

    // GEMM2: c2 = silu(c1@Wc2 + bc2); m-partials = sum c2*wc3 over this wave's cols
    {
        f32x4 acc[2][2] = {};
        const short8* pB = (const short8*)(pack + (size_t)PWC2 * 4096);
#pragma unroll
        for (int ks = 0; ks < 4; ++ks) {
            short8 b0 = pB[(ks * 8 + w * 2 + 0) * 64 + lane];
            short8 b1 = pB[(ks * 8 + w * 2 + 1) * 64 + lane];
#pragma unroll
            for (int mt = 0; mt < 2; ++mt) {
                const short8 a = *(const short8*)&ar_s[mt * 16 + l16][ks * 32 + quad * 8];
                acc[mt][0] = MFMA16(a, b0, acc[mt][0]);
                acc[mt][1] = MFMA16(a, b1, acc[mt][1]);
            }
        }
#pragma unroll
        for (int mt = 0; mt < 2; ++mt)
#pragma unroll
            for (int reg = 0; reg < 4; ++reg) {
                float p = siluf(acc[mt][0][reg] + bc2[0]) * wc3[0]
                        + siluf(acc[mt][1][reg] + bc2[1]) * wc3[1];
                p += __shfl_xor(p, 1); p += __shfl_xor(p, 2); p += __shfl_xor(p, 4); p += __shfl_xor(p, 8);
                if (l16 == 0) mp_s[w][mt * 16 + quad * 4 + reg] = p;
            }
    }
    __syncthreads();

    if (t < 32) {
        const float m = mp_s[0][t] + mp_s[1][t] + mp_s[2][t] + mp_s[3][t];
        const float tr = m * em_s[t];
        const int r4 = row_s[t] * 4;
        atomicAdd(&aggx[r4 + 0], cdx_s[t] * tr);
        atomicAdd(&aggx[r4 + 1], cdy_s[t] * tr);
        atomicAdd(&aggx[r4 + 2], cdz_s[t] * tr);
    }
}

// ---------------- coord epilogue ----------------
__global__ void k_coord(const float* __restrict__ x, const float* __restrict__ nmask,
                        const float* __restrict__ aggx, float* __restrict__ out_x, int N) {
    const int idx = blockIdx.x * blockDim.x + threadIdx.x;
    if (idx >= N * 3) return;
    const int i = idx / 3, d = idx - i * 3;
    out_x[idx] = (x[idx] + aggx[i * 4 + d] * (1.0f / 100.0f)) * nmask[i];
}

extern "C" void kernel_launch(void* const* d_in, const int* in_sizes, int n_in,
                              void* d_out, int out_size, void* d_ws, size_t ws_size,
                              hipStream_t stream) {
    const float* h     = (const float*)d_in[0];
    const float* x     = (const float*)d_in[1];
    const int*   eidx  = (const int*)d_in[2];
    const float* nmask = (const float*)d_in[3];
    const float* emask = (const float*)d_in[4];
    const float* eattr = (const float*)d_in[5];
    const float* W_lin = (const float*)d_in[6];
    const float* b_lin = (const float*)d_in[7];
    const float* We1   = (const float*)d_in[8];
    const float* be1   = (const float*)d_in[9];
    const float* We2   = (const float*)d_in[10];
    const float* be2   = (const float*)d_in[11];
    const float* Wn1   = (const float*)d_in[12];
    const float* bn1   = (const float*)d_in[13];
    const float* Wn2   = (const float*)d_in[14];
    const float* bn2   = (const float*)d_in[15];
    const float* Wa1   = (const float*)d_in[16];
    const float* ba1   = (const float*)d_in[17];
    const float* Wa2   = (const float*)d_in[18];
    const float* ba2   = (const float*)d_in[19];
    const float* ln_g  = (const float*)d_in[20];
    const float* ln_b  = (const float*)d_in[21];
    const float* Wc1   = (const float*)d_in[22];
    const float* bc1   = (const float*)d_in[23];
    const float* Wc2   = (const float*)d_in[24];
    const float* bc2   = (const float*)d_in[25];
    const float* Wc3   = (const float*)d_in[26];

    const int N = in_sizes[0] / D;
    const int E = in_sizes[2] / 2;

    // ws: hh f32 | agg | aggx | e3buf | hh1b | hh2b | pack (~36.5 MB)
    float*  hh    = (float*)d_ws;
    float*  agg   = hh + (size_t)N * D;
    float*  aggx  = agg + (size_t)N * D;
    float2* e3buf = (float2*)(aggx + (size_t)N * 4);
    ushort* hh1b  = (ushort*)(e3buf + (size_t)E);
    ushort* hh2b  = hh1b + (size_t)N * D;
    ushort* pack  = hh2b + (size_t)N * D;

    float* out_h = (float*)d_out;
    float* out_x = out_h + (size_t)N * D;

    const int EB = (E + 31) / 32;
    const int NB = (N + 63) / 64;

    k_zero<<<2048, 256, 0, stream>>>(agg, (long)N * D + (long)N * 4);
    k_packall<<<NPACK, 256, 0, stream>>>(W_lin, b_lin, Wa1, ba1, We1, be1, We2,
                                         Wn1, bn1, Wn2, Wc1, bc1, Wc2, pack);
    k_node_lin<<<NB, 256, 0, stream>>>(h, pack, hh, hh1b, N);
    k_edge1<<<EB, 256, 0, stream>>>(eidx, x, eattr, emask, hh1b, pack,
                                    Wa2, ba2, be2, agg, e3buf, E);
    k_node2<<<NB, 256, 0, stream>>>(agg, hh, pack, bn2, ln_g, ln_b, out_h, hh2b, N);
    k_edge2<<<EB, 256, 0, stream>>>(eidx, x, eattr, emask, hh2b, pack,
                                    bc2, Wc3, e3buf, aggx, E);
    k_coord<<<(N * 3 + 255) / 256, 256, 0, stream>>>(x, nmask, aggx, out_x, N);
}